// Round 2
// baseline (773.813 us; speedup 1.0000x reference)
//
#include <hip/hip_runtime.h>

#define IN_SIZE 256
#define OUT_SIZE 64
#define BSHIFT 7         // 128-row buckets
#define BROWS 128
#define BMASK 127
#define CAP 2560         // bucket capacity: mean 2046, sigma 45 -> +11 sigma
#define K1_EDGES 8192    // edges per coarse block (16 per thread, 512 threads)
#define WPAD 264         // 256+8 shorts, breaks LDS bank alias for W tile
#define HCH 32           // channels per gather half-block

typedef __attribute__((ext_vector_type(8))) short short8;   // 8 bf16, 4 VGPRs
typedef __attribute__((ext_vector_type(4))) float floatx4;  // MFMA acc

__device__ inline unsigned short f2bf(float f) {
  unsigned u = __builtin_bit_cast(unsigned, f);
  u += 0x7fff + ((u >> 16) & 1);  // round-to-nearest-even
  return (unsigned short)(u >> 16);
}
__device__ inline float bf2f(unsigned short u) {
  unsigned v = (unsigned)u << 16;
  return __builtin_bit_cast(float, v);
}

// ---------------------------------------------------------------------------
// K0: zero the coarse cursors (the only state atomics touch before K1).
__global__ __launch_bounds__(512) void zero_kernel(int* __restrict__ cursor) {
  int i = blockIdx.x * 512 + threadIdx.x;
  if (i < 1024) cursor[i] = 0;
}

// ---------------------------------------------------------------------------
// K1: heterogeneous grid. Blocks [0, nb_coarse): coarse bucketing by row>>7.
// Blocks [nb_coarse, ...): xwb = bf16(x @ W.T), NO dinv (deferred to gather;
// that is what makes this block-parallel with the bucketing). NO global count
// atomics (round-1 lesson: 1.6M random device-scope RMWs cost ~+100us).
// All 978 blocks co-resident at 4 blocks/CU @ 512 thr.
struct K1SM {
  union {
    int hist[1024];                    // coarse path (nbuck=782 <= 1024)
    unsigned short w[64 * WPAD];       // matmul path: W tile bf16 (33.8 KB)
  };
};

__global__ __launch_bounds__(512) void fused1_kernel(
    const int* __restrict__ row, const int* __restrict__ col,
    int* __restrict__ coarse_cursor, unsigned* __restrict__ pairs,
    const float* __restrict__ x, const float* __restrict__ W,
    unsigned short* __restrict__ xwb, int n_edges, int n_nodes, int nbuck,
    int nb_coarse) {
  __shared__ K1SM sm;
  int tid = threadIdx.x;
  int bid = blockIdx.x;

  if (bid < nb_coarse) {
    // ---- coarse bucketing ----
    sm.hist[tid] = 0;
    sm.hist[tid + 512] = 0;
    __syncthreads();

    int r[16], c[16];
    int ebase = bid * K1_EDGES + tid;
#pragma unroll
    for (int i = 0; i < 16; i++) {
      int e = ebase + i * 512;
      bool ok = e < n_edges;
      r[i] = ok ? row[e] : -1;
      c[i] = ok ? col[e] : -1;
      if (ok && r[i] != c[i]) atomicAdd(&sm.hist[r[i] >> BSHIFT], 1);
    }
    __syncthreads();

    for (int i = tid; i < nbuck; i += 512) {
      int cnt = sm.hist[i];
      if (cnt) sm.hist[i] = atomicAdd(&coarse_cursor[i], cnt);
    }
    __syncthreads();

#pragma unroll
    for (int i = 0; i < 16; i++) {
      if (r[i] >= 0 && r[i] != c[i]) {
        int bin = r[i] >> BSHIFT;
        int slot = atomicAdd(&sm.hist[bin], 1);
        if (slot < CAP)
          pairs[(size_t)bin * CAP + slot] =
              ((unsigned)(r[i] & BMASK) << 17) | (unsigned)c[i];
      }
    }
  } else {
    // ---- matmul: 128 nodes per block, W converted fp32->bf16 inline ----
    int mb = bid - nb_coarse;
    long nbase = (long)mb * 128;
    {
      int r = tid >> 3;  // 0..63
      int q = tid & 7;   // 8 chunks of 32 floats
      const float* src = W + (size_t)r * IN_SIZE + q * 32;
#pragma unroll
      for (int i = 0; i < 4; i++) {
        float4 a = *(const float4*)(src + i * 8);
        float4 b = *(const float4*)(src + i * 8 + 4);
        short8 s;
        s[0] = (short)f2bf(a.x); s[1] = (short)f2bf(a.y);
        s[2] = (short)f2bf(a.z); s[3] = (short)f2bf(a.w);
        s[4] = (short)f2bf(b.x); s[5] = (short)f2bf(b.y);
        s[6] = (short)f2bf(b.z); s[7] = (short)f2bf(b.w);
        *(short8*)(&sm.w[r * WPAD + q * 32 + i * 8]) = s;
      }
    }
    __syncthreads();

    int wave = tid >> 6;
    int lane = tid & 63;
    int quad = lane >> 4;
    int lcol = lane & 15;
    long node = nbase + wave * 16 + lcol;
    long nclamp = (node < (long)n_nodes) ? node : (long)(n_nodes - 1);
    const float* xrow = x + nclamp * IN_SIZE;

    floatx4 acc[4];
#pragma unroll
    for (int t = 0; t < 4; t++) acc[t] = (floatx4){0.f, 0.f, 0.f, 0.f};

#pragma unroll
    for (int kk = 0; kk < 8; kk++) {
      const float* p = xrow + kk * 32 + quad * 8;
      float4 a = *(const float4*)(p);
      float4 bb = *(const float4*)(p + 4);
      short8 bfrag;
      bfrag[0] = (short)f2bf(a.x);  bfrag[1] = (short)f2bf(a.y);
      bfrag[2] = (short)f2bf(a.z);  bfrag[3] = (short)f2bf(a.w);
      bfrag[4] = (short)f2bf(bb.x); bfrag[5] = (short)f2bf(bb.y);
      bfrag[6] = (short)f2bf(bb.z); bfrag[7] = (short)f2bf(bb.w);
#pragma unroll
      for (int t = 0; t < 4; t++) {
        short8 afrag =
            *(const short8*)(&sm.w[(t * 16 + lcol) * WPAD + kk * 32 + quad * 8]);
        acc[t] = __builtin_amdgcn_mfma_f32_16x16x32_bf16(afrag, bfrag, acc[t],
                                                         0, 0, 0);
      }
    }

    if (node < (long)n_nodes) {
#pragma unroll
      for (int t = 0; t < 4; t++) {
        ushort4 sv;
        sv.x = f2bf(acc[t][0]);
        sv.y = f2bf(acc[t][1]);
        sv.z = f2bf(acc[t][2]);
        sv.w = f2bf(acc[t][3]);
        *(ushort4*)(xwb + node * OUT_SIZE + t * 16 + quad * 4) = sv;
      }
    }
  }
}

// ---------------------------------------------------------------------------
// K2: per-bucket degree histogram -> dinv. Replaces round-1's global count
// atomics (1.6M random RMWs) with 782 local LDS histograms over pairs keys.
__global__ __launch_bounds__(256) void deg_kernel(
    const int* __restrict__ cursor, const unsigned* __restrict__ pairs,
    float* __restrict__ dinv, int n_nodes) {
  __shared__ int hist[BROWS];
  int tid = threadIdx.x;
  int b = blockIdx.x;
  size_t base = (size_t)b * CAP;
  int n_b = cursor[b];
  if (n_b > CAP) n_b = CAP;
  if (tid < BROWS) hist[tid] = 0;
  __syncthreads();
  for (int i = tid; i < n_b; i += 256)
    atomicAdd(&hist[pairs[base + i] >> 17], 1);
  __syncthreads();
  if (tid < BROWS) {
    int r = b * BROWS + tid;
    if (r < n_nodes) dinv[r] = rsqrtf((float)hist[tid] + 1.0f);
  }
}

// ---------------------------------------------------------------------------
// K3: edge-parallel gather-scatter. No CSR: each block owns one bucket-half
// (128 rows x 32 channels) and accumulates dinv[c]*xw[c] straight into an
// LDS float tile via ds_add_f32. [128][33] padding spreads the random rl
// across banks. 2 blocks/bucket (64B-sector channel split -> same HBM bytes,
// 2x blocks) + 2-edge unroll restore the MLP round-1 lost. Epilogue applies
// dinv[r] and the self-loop term.
__global__ __launch_bounds__(512) void gather_kernel(
    const int* __restrict__ cursor, const unsigned* __restrict__ pairs,
    const float* __restrict__ dinv, const unsigned short* __restrict__ xwb,
    float* __restrict__ out, int n_nodes) {
  __shared__ float acc[BROWS][HCH + 1];  // 16.9 KB
  int tid = threadIdx.x;
  int b = blockIdx.x >> 1;
  int half = blockIdx.x & 1;
  size_t base = (size_t)b * CAP;
  int n_b = cursor[b];
  if (n_b > CAP) n_b = CAP;

  for (int i = tid; i < BROWS * (HCH + 1); i += 512) ((float*)acc)[i] = 0.f;
  __syncthreads();

  int chunk = (tid & 3) * 8;  // 8 channels within the 32-ch half
  int coff = half * HCH + chunk;

  // 128 edges per block-iteration, 2 independent edges per lane for MLP.
  for (int j = tid >> 2; j < n_b; j += 256) {
    int i1 = j + 128;
    bool ok1 = i1 < n_b;
    unsigned p0 = pairs[base + j];
    unsigned p1 = ok1 ? pairs[base + i1] : p0;
    int c0 = p0 & 0x1FFFF;
    int c1 = p1 & 0x1FFFF;
    float dv0 = dinv[c0];
    float dv1 = dinv[c1];
    short8 v0 = *(const short8*)(xwb + (size_t)c0 * OUT_SIZE + coff);
    short8 v1 = *(const short8*)(xwb + (size_t)c1 * OUT_SIZE + coff);
    int rl0 = p0 >> 17;
    int rl1 = p1 >> 17;
#pragma unroll
    for (int k = 0; k < 8; k++)
      unsafeAtomicAdd(&acc[rl0][chunk + k], dv0 * bf2f((unsigned short)v0[k]));
    if (ok1) {
#pragma unroll
      for (int k = 0; k < 8; k++)
        unsafeAtomicAdd(&acc[rl1][chunk + k],
                        dv1 * bf2f((unsigned short)v1[k]));
    }
  }
  __syncthreads();

  // epilogue: out[r][half*32+chunk..+8] = dinv[r]*(acc + dinv[r]*xw[r])
  int rl = tid >> 2;
  int r = b * BROWS + rl;
  if (r < n_nodes) {
    float dr = dinv[r];
    short8 sv = *(const short8*)(xwb + (size_t)r * OUT_SIZE + coff);
    float o[8];
#pragma unroll
    for (int k = 0; k < 8; k++)
      o[k] = dr * (acc[rl][chunk + k] + dr * bf2f((unsigned short)sv[k]));
    float* dst = out + (size_t)r * OUT_SIZE + coff;
    *(float4*)(dst) = make_float4(o[0], o[1], o[2], o[3]);
    *(float4*)(dst + 4) = make_float4(o[4], o[5], o[6], o[7]);
  }
}

// ---------------------------------------------------------------------------
extern "C" void kernel_launch(void* const* d_in, const int* in_sizes, int n_in,
                              void* d_out, int out_size, void* d_ws,
                              size_t ws_size, hipStream_t stream) {
  const int* edge_index = (const int*)d_in[0];
  const float* x = (const float*)d_in[1];
  const float* W = (const float*)d_in[3];

  int n_edges = in_sizes[0] / 2;
  int n_nodes = in_sizes[1] / IN_SIZE;
  const int* row = edge_index;
  const int* col = edge_index + n_edges;
  float* out = (float*)d_out;

  int nbuck = (n_nodes + BROWS - 1) >> BSHIFT;          // 782
  int nb_coarse = (n_edges + K1_EDGES - 1) / K1_EDGES;  // 196
  int nb_mm = (n_nodes + 127) / 128;                    // 782

  // Workspace: coarse_cursor(4KB) | pairs[nbuck*CAP u32] (~8MB) |
  //            xwb[N*64 bf16] (12.8MB) | dinv[N f32] (400KB)
  char* ws = (char*)d_ws;
  int* coarse_cursor = (int*)ws;
  unsigned* pairs = (unsigned*)(ws + 4096);
  size_t pairsB = (size_t)nbuck * CAP * 4;  // 8,007,680 B
  unsigned short* xwb = (unsigned short*)(ws + 4096 + pairsB);
  float* dinv =
      (float*)(ws + 4096 + pairsB + (size_t)n_nodes * OUT_SIZE * 2);

  zero_kernel<<<2, 512, 0, stream>>>(coarse_cursor);
  fused1_kernel<<<nb_coarse + nb_mm, 512, 0, stream>>>(
      row, col, coarse_cursor, pairs, x, W, xwb, n_edges, n_nodes, nbuck,
      nb_coarse);
  deg_kernel<<<nbuck, 256, 0, stream>>>(coarse_cursor, pairs, dinv, n_nodes);
  gather_kernel<<<nbuck * 2, 512, 0, stream>>>(coarse_cursor, pairs, dinv,
                                               xwb, out, n_nodes);
}

// Round 3
// 255.765 us; speedup vs baseline: 3.0255x; 3.0255x over previous
//
#include <hip/hip_runtime.h>

#define IN_SIZE 256
#define OUT_SIZE 64
#define BSHIFT 7         // 128-row buckets
#define BROWS 128
#define BMASK 127
#define CAP 2560         // bucket capacity: mean 2046, sigma 45 -> +11 sigma
#define K1_EDGES 8192    // edges per coarse block (16 per thread, 512 threads)
#define WPAD 264         // 256+8 shorts, breaks LDS bank alias for W tile

typedef __attribute__((ext_vector_type(8))) short short8;   // 8 bf16, 4 VGPRs
typedef __attribute__((ext_vector_type(4))) float floatx4;  // MFMA acc

__device__ inline unsigned short f2bf(float f) {
  unsigned u = __builtin_bit_cast(unsigned, f);
  u += 0x7fff + ((u >> 16) & 1);  // round-to-nearest-even
  return (unsigned short)(u >> 16);
}
__device__ inline float bf2f(unsigned short u) {
  unsigned v = (unsigned)u << 16;
  return __builtin_bit_cast(float, v);
}

// ---------------------------------------------------------------------------
// K0: zero the coarse cursors.
__global__ __launch_bounds__(512) void zero_kernel(int* __restrict__ cursor) {
  int i = blockIdx.x * 512 + threadIdx.x;
  if (i < 1024) cursor[i] = 0;
}

// ---------------------------------------------------------------------------
// K1: heterogeneous grid. Blocks [0, nb_coarse): coarse bucketing by row>>7.
// Blocks [nb_coarse, ...): xwb = bf16(x @ W.T) with NO dinv (deferred to the
// gather) -- that is what makes matmul independent of bucketing so both run
// concurrently in one grid. No global count atomics (round-1 lesson: 1.6M
// random device RMWs ~ +50us).
struct K1SM {
  union {
    int hist[1024];                    // coarse path (nbuck=782 <= 1024)
    unsigned short w[64 * WPAD];       // matmul path: W tile bf16 (33.8 KB)
  };
};

__global__ __launch_bounds__(512) void fused1_kernel(
    const int* __restrict__ row, const int* __restrict__ col,
    int* __restrict__ coarse_cursor, unsigned* __restrict__ pairs,
    const float* __restrict__ x, const float* __restrict__ W,
    unsigned short* __restrict__ xwb, int n_edges, int n_nodes, int nbuck,
    int nb_coarse) {
  __shared__ K1SM sm;
  int tid = threadIdx.x;
  int bid = blockIdx.x;

  if (bid < nb_coarse) {
    // ---- coarse bucketing ----
    sm.hist[tid] = 0;
    sm.hist[tid + 512] = 0;
    __syncthreads();

    int r[16], c[16];
    int ebase = bid * K1_EDGES + tid;
#pragma unroll
    for (int i = 0; i < 16; i++) {
      int e = ebase + i * 512;
      bool ok = e < n_edges;
      r[i] = ok ? row[e] : -1;
      c[i] = ok ? col[e] : -1;
      if (ok && r[i] != c[i]) atomicAdd(&sm.hist[r[i] >> BSHIFT], 1);
    }
    __syncthreads();

    for (int i = tid; i < nbuck; i += 512) {
      int cnt = sm.hist[i];
      if (cnt) sm.hist[i] = atomicAdd(&coarse_cursor[i], cnt);
    }
    __syncthreads();

#pragma unroll
    for (int i = 0; i < 16; i++) {
      if (r[i] >= 0 && r[i] != c[i]) {
        int bin = r[i] >> BSHIFT;
        int slot = atomicAdd(&sm.hist[bin], 1);
        if (slot < CAP)
          pairs[(size_t)bin * CAP + slot] =
              ((unsigned)(r[i] & BMASK) << 17) | (unsigned)c[i];
      }
    }
  } else {
    // ---- matmul: 128 nodes per block, W converted fp32->bf16 inline ----
    int mb = bid - nb_coarse;
    long nbase = (long)mb * 128;
    {
      int r = tid >> 3;  // 0..63
      int q = tid & 7;   // 8 chunks of 32 floats
      const float* src = W + (size_t)r * IN_SIZE + q * 32;
#pragma unroll
      for (int i = 0; i < 4; i++) {
        float4 a = *(const float4*)(src + i * 8);
        float4 b = *(const float4*)(src + i * 8 + 4);
        short8 s;
        s[0] = (short)f2bf(a.x); s[1] = (short)f2bf(a.y);
        s[2] = (short)f2bf(a.z); s[3] = (short)f2bf(a.w);
        s[4] = (short)f2bf(b.x); s[5] = (short)f2bf(b.y);
        s[6] = (short)f2bf(b.z); s[7] = (short)f2bf(b.w);
        *(short8*)(&sm.w[r * WPAD + q * 32 + i * 8]) = s;
      }
    }
    __syncthreads();

    int wave = tid >> 6;
    int lane = tid & 63;
    int quad = lane >> 4;
    int lcol = lane & 15;
    long node = nbase + wave * 16 + lcol;
    long nclamp = (node < (long)n_nodes) ? node : (long)(n_nodes - 1);
    const float* xrow = x + nclamp * IN_SIZE;

    floatx4 acc[4];
#pragma unroll
    for (int t = 0; t < 4; t++) acc[t] = (floatx4){0.f, 0.f, 0.f, 0.f};

#pragma unroll
    for (int kk = 0; kk < 8; kk++) {
      const float* p = xrow + kk * 32 + quad * 8;
      float4 a = *(const float4*)(p);
      float4 bb = *(const float4*)(p + 4);
      short8 bfrag;
      bfrag[0] = (short)f2bf(a.x);  bfrag[1] = (short)f2bf(a.y);
      bfrag[2] = (short)f2bf(a.z);  bfrag[3] = (short)f2bf(a.w);
      bfrag[4] = (short)f2bf(bb.x); bfrag[5] = (short)f2bf(bb.y);
      bfrag[6] = (short)f2bf(bb.z); bfrag[7] = (short)f2bf(bb.w);
#pragma unroll
      for (int t = 0; t < 4; t++) {
        short8 afrag =
            *(const short8*)(&sm.w[(t * 16 + lcol) * WPAD + kk * 32 + quad * 8]);
        acc[t] = __builtin_amdgcn_mfma_f32_16x16x32_bf16(afrag, bfrag, acc[t],
                                                         0, 0, 0);
      }
    }

    if (node < (long)n_nodes) {
#pragma unroll
      for (int t = 0; t < 4; t++) {
        ushort4 sv;
        sv.x = f2bf(acc[t][0]);
        sv.y = f2bf(acc[t][1]);
        sv.z = f2bf(acc[t][2]);
        sv.w = f2bf(acc[t][3]);
        *(ushort4*)(xwb + node * OUT_SIZE + t * 16 + quad * 4) = sv;
      }
    }
  }
}

// ---------------------------------------------------------------------------
// K2: fine CSR build, single-pass (round-0 structure, verbatim): pairs ->
// LDS while histogramming, scan, scatter colsp; writes count/row_start/dinv.
__global__ __launch_bounds__(256) void fine_kernel(
    const int* __restrict__ coarse_cursor, const unsigned* __restrict__ pairs,
    unsigned* __restrict__ colsp, int* __restrict__ count,
    int* __restrict__ row_start, float* __restrict__ dinv, int n_nodes) {
  __shared__ unsigned lpair[CAP];  // 10 KB
  __shared__ int hist[BROWS];
  __shared__ int scn[BROWS];
  int tid = threadIdx.x;
  int b = blockIdx.x;
  size_t base = (size_t)b * CAP;
  int n_b = coarse_cursor[b];
  if (n_b > CAP) n_b = CAP;

  if (tid < BROWS) hist[tid] = 0;
  __syncthreads();

  for (int i = tid; i < n_b; i += 256) {  // copy + histogram in one pass
    unsigned p = pairs[base + i];
    lpair[i] = p;
    atomicAdd(&hist[p >> 17], 1);
  }
  __syncthreads();

  if (tid < BROWS) scn[tid] = hist[tid];
  __syncthreads();
  for (int off = 1; off < BROWS; off <<= 1) {
    int t = (tid >= off && tid < BROWS) ? scn[tid - off] : 0;
    __syncthreads();
    if (tid < BROWS) scn[tid] += t;
    __syncthreads();
  }

  if (tid < BROWS) {
    int e = (tid > 0) ? scn[tid - 1] : 0;
    int r = b * BROWS + tid;
    if (r < n_nodes) {
      int deg = hist[tid];
      count[r] = deg;
      row_start[r] = (int)base + e;
      dinv[r] = rsqrtf((float)deg + 1.0f);
    }
    hist[tid] = e;  // becomes scatter cursor
  }
  __syncthreads();

  for (int i = tid; i < n_b; i += 256) {
    unsigned p = lpair[i];
    int slot = atomicAdd(&hist[p >> 17], 1);
    colsp[base + slot] = p & 0x1FFFFu;
  }
}

// ---------------------------------------------------------------------------
// K3: CSR gather, round-0 structure verbatim (4 rows/wave, full-128B row
// reads by 8 cg-lanes, register accumulate + shuffle reduce). Only change:
// per-edge weight m = dinv[c] (xwb is dinv-free now); same-address across
// the 8 cg lanes -> 1 L2 request per edge, dinv (400KB) is L2-resident.
__global__ __launch_bounds__(256) void gather_kernel(
    const int* __restrict__ row_start, const int* __restrict__ count,
    const unsigned* __restrict__ colsp, const float* __restrict__ dinv,
    const unsigned short* __restrict__ xwb, float* __restrict__ out,
    int n_nodes) {
  int lane = threadIdx.x & 63;
  int wave = threadIdx.x >> 6;
  int sub = lane & 7;   // edge slot
  int cg = lane >> 3;   // channels cg*8 .. cg*8+7
  int rb = (blockIdx.x * 4 + wave) * 4;  // first of 4 rows
  if (rb >= n_nodes) return;

  int start[4], cnt[4];
  int maxc = 0;
#pragma unroll
  for (int i = 0; i < 4; i++) {
    int r = rb + i;
    bool ok = r < n_nodes;
    start[i] = ok ? row_start[r] : 0;
    cnt[i] = ok ? count[r] : 0;
    maxc = max(maxc, cnt[i]);
  }

  float acc[4][8];
#pragma unroll
  for (int i = 0; i < 4; i++)
#pragma unroll
    for (int k = 0; k < 8; k++) acc[i][k] = 0.f;

  if (sub == 0) {  // self-loop terms: dinv[r]*xw[r]
#pragma unroll
    for (int i = 0; i < 4; i++) {
      int r = rb + i;
      if (r < n_nodes) {
        float dv = dinv[r];
        short8 v = *(const short8*)(xwb + (size_t)r * OUT_SIZE + cg * 8);
#pragma unroll
        for (int k = 0; k < 8; k++) acc[i][k] = dv * bf2f((unsigned short)v[k]);
      }
    }
  }

  for (int j = 0; j < maxc; j += 8) {
    int c[4];
    float m[4];
    int idx = j + sub;
#pragma unroll
    for (int i = 0; i < 4; i++) {
      bool act = idx < cnt[i];
      c[i] = act ? (int)colsp[start[i] + idx] : rb;  // dummy -> hot line
      m[i] = act ? dinv[c[i]] : 0.0f;
    }
    short8 v[4];
#pragma unroll
    for (int i = 0; i < 4; i++)
      v[i] = *(const short8*)(xwb + (size_t)c[i] * OUT_SIZE + cg * 8);
#pragma unroll
    for (int i = 0; i < 4; i++)
#pragma unroll
      for (int k = 0; k < 8; k++)
        acc[i][k] += m[i] * bf2f((unsigned short)v[i][k]);
  }

#pragma unroll
  for (int i = 0; i < 4; i++)
#pragma unroll
    for (int k = 0; k < 8; k++) {
      acc[i][k] += __shfl_xor(acc[i][k], 1);
      acc[i][k] += __shfl_xor(acc[i][k], 2);
      acc[i][k] += __shfl_xor(acc[i][k], 4);
    }

  if (sub == 0) {
#pragma unroll
    for (int i = 0; i < 4; i++) {
      int r = rb + i;
      if (r < n_nodes) {
        float dr = dinv[r];
        float* dst = out + (size_t)r * OUT_SIZE + cg * 8;
        *(float4*)(dst) =
            make_float4(dr * acc[i][0], dr * acc[i][1], dr * acc[i][2],
                        dr * acc[i][3]);
        *(float4*)(dst + 4) =
            make_float4(dr * acc[i][4], dr * acc[i][5], dr * acc[i][6],
                        dr * acc[i][7]);
      }
    }
  }
}

// ---------------------------------------------------------------------------
extern "C" void kernel_launch(void* const* d_in, const int* in_sizes, int n_in,
                              void* d_out, int out_size, void* d_ws,
                              size_t ws_size, hipStream_t stream) {
  const int* edge_index = (const int*)d_in[0];
  const float* x = (const float*)d_in[1];
  const float* W = (const float*)d_in[3];

  int n_edges = in_sizes[0] / 2;
  int n_nodes = in_sizes[1] / IN_SIZE;
  const int* row = edge_index;
  const int* col = edge_index + n_edges;
  float* out = (float*)d_out;

  int nbuck = (n_nodes + BROWS - 1) >> BSHIFT;          // 782
  int nb_coarse = (n_edges + K1_EDGES - 1) / K1_EDGES;  // 196
  int nb_mm = (n_nodes + 127) / 128;                    // 782

  // Workspace: count[N] | row_start[N] | dinv[N] | coarse_cursor(4KB) |
  //            pairs[nbuck*CAP u32] | colsp[nbuck*CAP u32] | xwb[N*64 bf16]
  char* ws = (char*)d_ws;
  size_t nb4 = ((size_t)n_nodes * 4 + 15) & ~(size_t)15;
  int* count = (int*)ws;
  int* row_start = (int*)(ws + nb4);
  float* dinv = (float*)(ws + 2 * nb4);
  int* coarse_cursor = (int*)(ws + 3 * nb4);
  size_t pairsB = (size_t)nbuck * CAP * 4;  // 8,007,680 B
  unsigned* pairs = (unsigned*)(ws + 3 * nb4 + 4096);
  unsigned* colsp = (unsigned*)(ws + 3 * nb4 + 4096 + pairsB);
  unsigned short* xwb =
      (unsigned short*)(ws + 3 * nb4 + 4096 + 2 * pairsB);

  zero_kernel<<<2, 512, 0, stream>>>(coarse_cursor);
  fused1_kernel<<<nb_coarse + nb_mm, 512, 0, stream>>>(
      row, col, coarse_cursor, pairs, x, W, xwb, n_edges, n_nodes, nbuck,
      nb_coarse);
  fine_kernel<<<nbuck, 256, 0, stream>>>(coarse_cursor, pairs, colsp, count,
                                         row_start, dinv, n_nodes);
  gather_kernel<<<(n_nodes + 15) / 16, 256, 0, stream>>>(
      row_start, count, colsp, dinv, xwb, out, n_nodes);
}